// Round 1
// baseline (165.109 us; speedup 1.0000x reference)
//
#include <hip/hip_runtime.h>
#include <hip/hip_bf16.h>

// Head: x[8,2048,768] fp32; Wk,Wq,Wv [768,64] fp32 -> out[8,2048,64] fp32
// q=xWq k=xWk v=xWv; att=softmax(q k^T/8); out=att v   (no causal mask)

#define BATCH 8
#define SEQ   2048
#define CEMB  768
#define HEADD 64
#define LOG2E 1.4426950408889634f

typedef __attribute__((ext_vector_type(4))) float f32x4;
typedef __attribute__((ext_vector_type(8))) short short8;
typedef __attribute__((ext_vector_type(4))) float fvec4;
typedef __attribute__((ext_vector_type(4))) unsigned short u16x4;

__device__ __forceinline__ unsigned short f2bf(float f) {
    unsigned int u = __builtin_bit_cast(unsigned int, f);
    u += 0x7fffu + ((u >> 16) & 1u);   // round-to-nearest-even
    return (unsigned short)(u >> 16);
}

// ---------------- kernel 1: W -> W^T bf16  (wt[3][64][768]) ----------------
__global__ void wt_kernel(const float* __restrict__ Wq, const float* __restrict__ Wk,
                          const float* __restrict__ Wv, unsigned short* __restrict__ wt) {
    int idx = blockIdx.x * 256 + threadIdx.x;   // 3*64*768 = 147456
    int o = idx / 49152;
    int r = idx % 49152;
    int n = r / 768;
    int k = r % 768;
    const float* W = (o == 0) ? Wq : (o == 1) ? Wk : Wv;
    wt[idx] = f2bf(W[k * 64 + n]);
}

// ---------------- kernel 2: projections q,k (row-major), v (transposed) ----
__global__ __launch_bounds__(256) void proj_kernel(
        const float* __restrict__ x, const unsigned short* __restrict__ wt,
        unsigned short* __restrict__ qg, unsigned short* __restrict__ kg,
        unsigned short* __restrict__ vtg) {
    __shared__ __align__(16) unsigned short xl[64][72];
    __shared__ __align__(16) unsigned short wl[3][64][72];

    const int tid = threadIdx.x;
    const int lane = tid & 63;
    const int wv = tid >> 6;        // wave 0..3
    const int qb = wv * 16;         // wave's 16 rows
    const int l15 = lane & 15;
    const int lq = lane >> 4;       // 0..3
    const int row0 = blockIdx.x * 64;

    f32x4 acc[3][4];
    for (int o = 0; o < 3; ++o)
        for (int f = 0; f < 4; ++f)
            acc[o][f] = f32x4{0.f, 0.f, 0.f, 0.f};

    for (int step = 0; step < 12; ++step) {
        const int k0 = step * 64;
        // stage x tile [64][64] fp32 -> bf16 LDS
        for (int c = tid; c < 1024; c += 256) {
            int m = c >> 4;
            int kk = (c & 15) << 2;
            fvec4 v = *reinterpret_cast<const fvec4*>(&x[(size_t)(row0 + m) * CEMB + k0 + kk]);
            u16x4 u;
            u[0] = f2bf(v[0]); u[1] = f2bf(v[1]); u[2] = f2bf(v[2]); u[3] = f2bf(v[3]);
            *reinterpret_cast<u16x4*>(&xl[m][kk]) = u;
        }
        // stage 3x W^T tiles [64][64] bf16
        for (int c = tid; c < 3072; c += 256) {
            int o = c >> 10;
            int r = c & 1023;
            int n = r >> 4;
            int kk = (r & 15) << 2;
            *reinterpret_cast<u16x4*>(&wl[o][n][kk]) =
                *reinterpret_cast<const u16x4*>(&wt[o * 49152 + n * 768 + k0 + kk]);
        }
        __syncthreads();

        short8 a0 = *reinterpret_cast<const short8*>(&xl[qb + l15][lq * 8]);
        short8 a1 = *reinterpret_cast<const short8*>(&xl[qb + l15][32 + lq * 8]);
        for (int o = 0; o < 3; ++o) {
            for (int f = 0; f < 4; ++f) {
                short8 b0 = *reinterpret_cast<const short8*>(&wl[o][f * 16 + l15][lq * 8]);
                short8 b1 = *reinterpret_cast<const short8*>(&wl[o][f * 16 + l15][32 + lq * 8]);
                acc[o][f] = __builtin_amdgcn_mfma_f32_16x16x32_bf16(a0, b0, acc[o][f], 0, 0, 0);
                acc[o][f] = __builtin_amdgcn_mfma_f32_16x16x32_bf16(a1, b1, acc[o][f], 0, 0, 0);
            }
        }
        __syncthreads();
    }

    // epilogue: q,k row-major via LDS repack (coalesced 16B stores)
    for (int o = 0; o < 2; ++o) {
        unsigned short* dst = o ? kg : qg;
        for (int f = 0; f < 4; ++f)
            for (int r = 0; r < 4; ++r)
                xl[qb + lq * 4 + r][f * 16 + l15] = f2bf(acc[o][f][r]);
        __syncthreads();
        for (int c = tid; c < 512; c += 256) {
            int m = c >> 3;
            int h0 = (c & 7) << 3;
            *reinterpret_cast<short8*>(&dst[(size_t)(row0 + m) * 64 + h0]) =
                *reinterpret_cast<const short8*>(&xl[m][h0]);
        }
        __syncthreads();
    }
    // v transposed: vtg[b][h][t]
    for (int f = 0; f < 4; ++f)
        for (int r = 0; r < 4; ++r)
            xl[f * 16 + l15][qb + lq * 4 + r] = f2bf(acc[2][f][r]);   // xl[h][m]
    __syncthreads();
    {
        const int b = row0 >> 11;
        const int t0 = row0 & 2047;
        for (int c = tid; c < 512; c += 256) {
            int h = c >> 3;
            int tt = (c & 7) << 3;
            *reinterpret_cast<short8*>(&vtg[(size_t)b * 64 * SEQ + (size_t)h * SEQ + t0 + tt]) =
                *reinterpret_cast<const short8*>(&xl[h][tt]);
        }
    }
}

// ---------------- kernel 3: flash attention -------------------------------
__global__ __launch_bounds__(256) void attn_kernel(
        const unsigned short* __restrict__ qg, const unsigned short* __restrict__ kg,
        const unsigned short* __restrict__ vtg, float* __restrict__ out) {
    __shared__ __align__(16) unsigned short ql[64][72];
    __shared__ __align__(16) unsigned short kl[64][72];
    __shared__ __align__(16) unsigned short vtl[64][72];
    __shared__ __align__(16) unsigned short pl[64][72];

    const int tid = threadIdx.x;
    const int lane = tid & 63;
    const int wv = tid >> 6;
    const int qb = wv * 16;
    const int l15 = lane & 15;
    const int lq = lane >> 4;
    const int b = blockIdx.x >> 5;       // batch
    const int qt = blockIdx.x & 31;      // query tile
    const size_t qrow0 = (size_t)b * SEQ + (size_t)qt * 64;

    // stage Q tile once
    for (int c = tid; c < 512; c += 256) {
        int m = c >> 3;
        int h0 = (c & 7) << 3;
        *reinterpret_cast<short8*>(&ql[m][h0]) =
            *reinterpret_cast<const short8*>(&qg[(qrow0 + m) * 64 + h0]);
    }
    __syncthreads();
    const short8 a0 = *reinterpret_cast<const short8*>(&ql[qb + l15][lq * 8]);
    const short8 a1 = *reinterpret_cast<const short8*>(&ql[qb + l15][32 + lq * 8]);

    f32x4 o_acc[4];
    for (int f = 0; f < 4; ++f) o_acc[f] = f32x4{0.f, 0.f, 0.f, 0.f};
    float m_run[4], l_run[4];
    for (int r = 0; r < 4; ++r) { m_run[r] = -1e30f; l_run[r] = 0.f; }

    for (int kt = 0; kt < 32; ++kt) {
        const size_t krow0 = (size_t)b * SEQ + (size_t)kt * 64;
        for (int c = tid; c < 512; c += 256) {
            int m = c >> 3;
            int h0 = (c & 7) << 3;
            *reinterpret_cast<short8*>(&kl[m][h0]) =
                *reinterpret_cast<const short8*>(&kg[(krow0 + m) * 64 + h0]);
        }
        const size_t vbase = (size_t)b * 64 * SEQ + (size_t)kt * 64;
        for (int c = tid; c < 512; c += 256) {
            int h = c >> 3;
            int cc0 = (c & 7) << 3;
            *reinterpret_cast<short8*>(&vtl[h][cc0]) =
                *reinterpret_cast<const short8*>(&vtg[vbase + (size_t)h * SEQ + cc0]);
        }
        __syncthreads();

        // S = Q K^T  (rows m = qb+(lq*4+r), cols n = f*16+l15)
        f32x4 s[4];
        for (int f = 0; f < 4; ++f) {
            s[f] = f32x4{0.f, 0.f, 0.f, 0.f};
            short8 b0 = *reinterpret_cast<const short8*>(&kl[f * 16 + l15][lq * 8]);
            s[f] = __builtin_amdgcn_mfma_f32_16x16x32_bf16(a0, b0, s[f], 0, 0, 0);
            short8 b1 = *reinterpret_cast<const short8*>(&kl[f * 16 + l15][32 + lq * 8]);
            s[f] = __builtin_amdgcn_mfma_f32_16x16x32_bf16(a1, b1, s[f], 0, 0, 0);
        }
        for (int f = 0; f < 4; ++f) s[f] *= 0.125f;   // 1/sqrt(64)

        // online softmax
        float mnew[4], alpha[4], rsum[4];
        for (int r = 0; r < 4; ++r) {
            float mx = fmaxf(fmaxf(s[0][r], s[1][r]), fmaxf(s[2][r], s[3][r]));
            for (int off = 1; off < 16; off <<= 1)
                mx = fmaxf(mx, __shfl_xor(mx, off));
            mnew[r] = fmaxf(m_run[r], mx);
            alpha[r] = exp2f((m_run[r] - mnew[r]) * LOG2E);
            rsum[r] = 0.f;
        }
        for (int f = 0; f < 4; ++f) {
            for (int r = 0; r < 4; ++r) {
                float pv = exp2f((s[f][r] - mnew[r]) * LOG2E);
                rsum[r] += pv;
                pl[qb + lq * 4 + r][f * 16 + l15] = f2bf(pv);
            }
        }
        for (int r = 0; r < 4; ++r) {
            for (int off = 1; off < 16; off <<= 1)
                rsum[r] += __shfl_xor(rsum[r], off);
            l_run[r] = l_run[r] * alpha[r] + rsum[r];
            m_run[r] = mnew[r];
        }
        for (int f = 0; f < 4; ++f)
            for (int r = 0; r < 4; ++r)
                o_acc[f][r] *= alpha[r];

        // O += P V   (A rows = qb+l15 are wave-local -> no barrier needed for pl)
        short8 pa0 = *reinterpret_cast<const short8*>(&pl[qb + l15][lq * 8]);
        short8 pa1 = *reinterpret_cast<const short8*>(&pl[qb + l15][32 + lq * 8]);
        for (int f = 0; f < 4; ++f) {
            short8 b0 = *reinterpret_cast<const short8*>(&vtl[f * 16 + l15][lq * 8]);
            o_acc[f] = __builtin_amdgcn_mfma_f32_16x16x32_bf16(pa0, b0, o_acc[f], 0, 0, 0);
            short8 b1 = *reinterpret_cast<const short8*>(&vtl[f * 16 + l15][32 + lq * 8]);
            o_acc[f] = __builtin_amdgcn_mfma_f32_16x16x32_bf16(pa1, b1, o_acc[f], 0, 0, 0);
        }
        __syncthreads();
    }

    for (int f = 0; f < 4; ++f)
        for (int r = 0; r < 4; ++r) {
            int m = qb + lq * 4 + r;
            int h = f * 16 + l15;
            out[(qrow0 + m) * 64 + h] = o_acc[f][r] / l_run[r];
        }
}

extern "C" void kernel_launch(void* const* d_in, const int* in_sizes, int n_in,
                              void* d_out, int out_size, void* d_ws, size_t ws_size,
                              hipStream_t stream) {
    (void)in_sizes; (void)n_in; (void)out_size; (void)ws_size;
    const float* x  = (const float*)d_in[0];
    const float* Wk = (const float*)d_in[1];   // setup_inputs order: x, Wk, Wq, Wv
    const float* Wq = (const float*)d_in[2];
    const float* Wv = (const float*)d_in[3];
    float* out = (float*)d_out;

    unsigned short* ws = (unsigned short*)d_ws;
    unsigned short* qg  = ws;                      // 16384*64
    unsigned short* kg  = ws + 1048576;            // 16384*64
    unsigned short* vtg = ws + 2097152;            // 8*64*2048
    unsigned short* wt  = ws + 3145728;            // 3*64*768

    wt_kernel<<<576, 256, 0, stream>>>(Wq, Wk, Wv, wt);
    proj_kernel<<<256, 256, 0, stream>>>(x, wt, qg, kg, vtg);
    attn_kernel<<<256, 256, 0, stream>>>(qg, kg, vtg, out);
}

// Round 2
// 129.064 us; speedup vs baseline: 1.2793x; 1.2793x over previous
//
#include <hip/hip_runtime.h>
#include <hip/hip_bf16.h>

// Head: x[8,2048,768] fp32; Wk,Wq,Wv [768,64] fp32 -> out[8,2048,64] fp32
// q=xWq k=xWk v=xWv; att=softmax(q k^T/8); out=att v   (no causal mask)
//
// R2 design: all-wave-independent, barrier-free streams.
//  - proj: 1024 blocks x 1 wave, 16 rows each; A from fp32 x via regs,
//    B (W^T bf16, L2-resident) direct from global; no staging LDS.
//  - attn: 1024 blocks x 1 wave, 16 query rows each; K/V fragments direct
//    from L2 with 2-deep register double-buffer; P via wave-local LDS.

#define BATCH 8
#define SEQ   2048
#define CEMB  768
#define HEADD 64
// 0.125 (1/sqrt(64)) * log2(e): pre-scale logits so exp2 is direct
#define SCL 0.18033688011112042f

typedef __attribute__((ext_vector_type(4))) float f32x4;
typedef __attribute__((ext_vector_type(8))) short short8;
typedef __attribute__((ext_vector_type(4))) float fvec4;

__device__ __forceinline__ unsigned short f2bf(float f) {
    unsigned int u = __builtin_bit_cast(unsigned int, f);
    u += 0x7fffu + ((u >> 16) & 1u);   // round-to-nearest-even
    return (unsigned short)(u >> 16);
}

// ---------------- kernel 1: W -> W^T bf16  (wt[3][64][768]) ----------------
__global__ void wt_kernel(const float* __restrict__ Wq, const float* __restrict__ Wk,
                          const float* __restrict__ Wv, unsigned short* __restrict__ wt) {
    int idx = blockIdx.x * 256 + threadIdx.x;   // 3*64*768 = 147456
    int o = idx / 49152;
    int r = idx % 49152;
    int n = r / 768;
    int k = r % 768;
    const float* W = (o == 0) ? Wq : (o == 1) ? Wk : Wv;
    wt[idx] = f2bf(W[k * 64 + n]);
}

// ---------------- kernel 2: projections, 1 wave / 16 rows, no staging -----
__global__ __launch_bounds__(64) void proj_kernel(
        const float* __restrict__ x, const unsigned short* __restrict__ wt,
        unsigned short* __restrict__ qg, unsigned short* __restrict__ kg,
        unsigned short* __restrict__ vtg) {
    __shared__ __align__(16) unsigned short lds_qk[16][72];
    __shared__ __align__(16) unsigned short lds_v[64][20];

    const int lane = threadIdx.x & 63;
    const int l15 = lane & 15;
    const int lq = lane >> 4;
    const int row0 = blockIdx.x * 16;

    f32x4 acc[12];
    #pragma unroll
    for (int i = 0; i < 12; ++i) acc[i] = f32x4{0.f, 0.f, 0.f, 0.f};

    for (int step = 0; step < 12; ++step) {
        const int k0 = step * 64;
        const float* xr = &x[(size_t)(row0 + l15) * CEMB + k0 + lq * 8];
        fvec4 x0 = *reinterpret_cast<const fvec4*>(xr);
        fvec4 x1 = *reinterpret_cast<const fvec4*>(xr + 4);
        fvec4 x2 = *reinterpret_cast<const fvec4*>(xr + 32);
        fvec4 x3 = *reinterpret_cast<const fvec4*>(xr + 36);
        short8 a0, a1;
        #pragma unroll
        for (int j = 0; j < 4; ++j) {
            a0[j]     = (short)f2bf(x0[j]);
            a0[4 + j] = (short)f2bf(x1[j]);
            a1[j]     = (short)f2bf(x2[j]);
            a1[4 + j] = (short)f2bf(x3[j]);
        }
        #pragma unroll
        for (int o = 0; o < 3; ++o) {
            #pragma unroll
            for (int f = 0; f < 4; ++f) {
                const unsigned short* wp =
                    &wt[o * 49152 + (f * 16 + l15) * CEMB + k0 + lq * 8];
                short8 b0 = *reinterpret_cast<const short8*>(wp);
                short8 b1 = *reinterpret_cast<const short8*>(wp + 32);
                acc[o * 4 + f] = __builtin_amdgcn_mfma_f32_16x16x32_bf16(a0, b0, acc[o * 4 + f], 0, 0, 0);
                acc[o * 4 + f] = __builtin_amdgcn_mfma_f32_16x16x32_bf16(a1, b1, acc[o * 4 + f], 0, 0, 0);
            }
        }
    }

    // epilogue q, k: wave-local LDS repack -> coalesced 16B stores
    #pragma unroll
    for (int o = 0; o < 2; ++o) {
        unsigned short* dst = o ? kg : qg;
        #pragma unroll
        for (int f = 0; f < 4; ++f)
            #pragma unroll
            for (int r = 0; r < 4; ++r)
                lds_qk[lq * 4 + r][f * 16 + l15] = f2bf(acc[o * 4 + f][r]);
        __syncthreads();
        #pragma unroll
        for (int i = 0; i < 2; ++i) {
            int chunk = lane + 64 * i;
            int m = chunk >> 3;
            int c0 = (chunk & 7) * 8;
            *reinterpret_cast<short8*>(&dst[(size_t)(row0 + m) * 64 + c0]) =
                *reinterpret_cast<const short8*>(&lds_qk[m][c0]);
        }
        __syncthreads();
    }
    // epilogue v: transpose to vtg[b][h][t]
    #pragma unroll
    for (int f = 0; f < 4; ++f)
        #pragma unroll
        for (int r = 0; r < 4; ++r)
            lds_v[f * 16 + l15][lq * 4 + r] = f2bf(acc[8 + f][r]);
    __syncthreads();
    {
        const int bb = row0 >> 11;
        const int t0 = row0 & 2047;
        unsigned short* vp = &vtg[(size_t)bb * 64 * SEQ + (size_t)lane * SEQ + t0];
        *reinterpret_cast<short8*>(vp)     = *reinterpret_cast<const short8*>(&lds_v[lane][0]);
        *reinterpret_cast<short8*>(vp + 8) = *reinterpret_cast<const short8*>(&lds_v[lane][8]);
    }
}

// ---------------- kernel 3: flash attention, 1 wave / 16 q-rows -----------
#define LOADKF(DST, KT) do {                                                         \
    const unsigned short* kp_ = kbase + (size_t)(KT) * 64 * 64;                      \
    _Pragma("unroll")                                                                \
    for (int f_ = 0; f_ < 4; ++f_) {                                                 \
        DST[2 * f_]     = *reinterpret_cast<const short8*>(&kp_[(f_ * 16 + l15) * 64 + lq * 8]);      \
        DST[2 * f_ + 1] = *reinterpret_cast<const short8*>(&kp_[(f_ * 16 + l15) * 64 + 32 + lq * 8]); \
    }                                                                                \
} while (0)

#define LOADVF(DST, KT) do {                                                         \
    const unsigned short* vp_ = vbase + (size_t)(KT) * 64;                           \
    _Pragma("unroll")                                                                \
    for (int f_ = 0; f_ < 4; ++f_) {                                                 \
        DST[2 * f_]     = *reinterpret_cast<const short8*>(&vp_[(size_t)(f_ * 16 + l15) * SEQ + lq * 8]);      \
        DST[2 * f_ + 1] = *reinterpret_cast<const short8*>(&vp_[(size_t)(f_ * 16 + l15) * SEQ + 32 + lq * 8]); \
    }                                                                                \
} while (0)

#define ITER(CK, CV, NK, NV, KT) do {                                                \
    if ((KT) + 1 < 32) { LOADKF(NK, (KT) + 1); LOADVF(NV, (KT) + 1); }               \
    f32x4 s[4];                                                                      \
    _Pragma("unroll")                                                                \
    for (int f = 0; f < 4; ++f) {                                                    \
        s[f] = f32x4{0.f, 0.f, 0.f, 0.f};                                            \
        s[f] = __builtin_amdgcn_mfma_f32_16x16x32_bf16(a0, CK[2 * f], s[f], 0, 0, 0);     \
        s[f] = __builtin_amdgcn_mfma_f32_16x16x32_bf16(a1, CK[2 * f + 1], s[f], 0, 0, 0); \
    }                                                                                \
    _Pragma("unroll")                                                                \
    for (int f = 0; f < 4; ++f) s[f] *= SCL;                                         \
    float mnew[4], alpha[4], rsum[4];                                                \
    _Pragma("unroll")                                                                \
    for (int r = 0; r < 4; ++r) {                                                    \
        float mx = fmaxf(fmaxf(s[0][r], s[1][r]), fmaxf(s[2][r], s[3][r]));          \
        mx = fmaxf(mx, __shfl_xor(mx, 1));                                           \
        mx = fmaxf(mx, __shfl_xor(mx, 2));                                           \
        mx = fmaxf(mx, __shfl_xor(mx, 4));                                           \
        mx = fmaxf(mx, __shfl_xor(mx, 8));                                           \
        mnew[r] = fmaxf(m_run[r], mx);                                               \
        alpha[r] = exp2f(m_run[r] - mnew[r]);                                        \
        m_run[r] = mnew[r];                                                          \
        rsum[r] = 0.f;                                                               \
    }                                                                                \
    _Pragma("unroll")                                                                \
    for (int f = 0; f < 4; ++f)                                                      \
        _Pragma("unroll")                                                            \
        for (int r = 0; r < 4; ++r) {                                                \
            float pv = exp2f(s[f][r] - mnew[r]);                                     \
            rsum[r] += pv;                                                           \
            pl[lq * 4 + r][f * 16 + l15] = f2bf(pv);                                 \
        }                                                                            \
    _Pragma("unroll")                                                                \
    for (int r = 0; r < 4; ++r) {                                                    \
        rsum[r] += __shfl_xor(rsum[r], 1);                                           \
        rsum[r] += __shfl_xor(rsum[r], 2);                                           \
        rsum[r] += __shfl_xor(rsum[r], 4);                                           \
        rsum[r] += __shfl_xor(rsum[r], 8);                                           \
        l_run[r] = l_run[r] * alpha[r] + rsum[r];                                    \
    }                                                                                \
    _Pragma("unroll")                                                                \
    for (int f = 0; f < 4; ++f)                                                      \
        _Pragma("unroll")                                                            \
        for (int r = 0; r < 4; ++r) o_acc[f][r] *= alpha[r];                         \
    short8 pa0 = *reinterpret_cast<const short8*>(&pl[l15][lq * 8]);                 \
    short8 pa1 = *reinterpret_cast<const short8*>(&pl[l15][32 + lq * 8]);            \
    _Pragma("unroll")                                                                \
    for (int f = 0; f < 4; ++f) {                                                    \
        o_acc[f] = __builtin_amdgcn_mfma_f32_16x16x32_bf16(pa0, CV[2 * f], o_acc[f], 0, 0, 0);     \
        o_acc[f] = __builtin_amdgcn_mfma_f32_16x16x32_bf16(pa1, CV[2 * f + 1], o_acc[f], 0, 0, 0); \
    }                                                                                \
} while (0)

__global__ __launch_bounds__(64) void attn_kernel(
        const unsigned short* __restrict__ qg, const unsigned short* __restrict__ kg,
        const unsigned short* __restrict__ vtg, float* __restrict__ out) {
    __shared__ __align__(16) unsigned short pl[16][72];

    const int lane = threadIdx.x & 63;
    const int l15 = lane & 15;
    const int lq = lane >> 4;
    const int b = blockIdx.x >> 7;        // batch 0..7
    const int qt = blockIdx.x & 127;      // 16-row query tile 0..127
    const size_t qrow0 = (size_t)b * SEQ + (size_t)qt * 16;

    const unsigned short* kbase = &kg[(size_t)b * SEQ * 64];
    const unsigned short* vbase = &vtg[(size_t)b * 64 * SEQ];

    const short8 a0 = *reinterpret_cast<const short8*>(&qg[(qrow0 + l15) * 64 + lq * 8]);
    const short8 a1 = *reinterpret_cast<const short8*>(&qg[(qrow0 + l15) * 64 + 32 + lq * 8]);

    f32x4 o_acc[4];
    #pragma unroll
    for (int f = 0; f < 4; ++f) o_acc[f] = f32x4{0.f, 0.f, 0.f, 0.f};
    float m_run[4], l_run[4];
    #pragma unroll
    for (int r = 0; r < 4; ++r) { m_run[r] = -1e30f; l_run[r] = 0.f; }

    short8 kf0[8], vf0[8], kf1[8], vf1[8];
    LOADKF(kf0, 0);
    LOADVF(vf0, 0);

    for (int kt = 0; kt < 32; kt += 2) {
        ITER(kf0, vf0, kf1, vf1, kt);
        ITER(kf1, vf1, kf0, vf0, kt + 1);
    }

    #pragma unroll
    for (int r = 0; r < 4; ++r) {
        float inv = 1.0f / l_run[r];
        #pragma unroll
        for (int f = 0; f < 4; ++f)
            out[(qrow0 + lq * 4 + r) * 64 + f * 16 + l15] = o_acc[f][r] * inv;
    }
}

extern "C" void kernel_launch(void* const* d_in, const int* in_sizes, int n_in,
                              void* d_out, int out_size, void* d_ws, size_t ws_size,
                              hipStream_t stream) {
    (void)in_sizes; (void)n_in; (void)out_size; (void)ws_size;
    const float* x  = (const float*)d_in[0];
    const float* Wk = (const float*)d_in[1];   // setup_inputs order: x, Wk, Wq, Wv
    const float* Wq = (const float*)d_in[2];
    const float* Wv = (const float*)d_in[3];
    float* out = (float*)d_out;

    unsigned short* ws = (unsigned short*)d_ws;
    unsigned short* qg  = ws;                      // 16384*64
    unsigned short* kg  = ws + 1048576;            // 16384*64
    unsigned short* vtg = ws + 2097152;            // 8*64*2048
    unsigned short* wt  = ws + 3145728;            // 3*64*768

    wt_kernel<<<576, 256, 0, stream>>>(Wq, Wk, Wv, wt);
    proj_kernel<<<1024, 64, 0, stream>>>(x, wt, qg, kg, vtg);
    attn_kernel<<<1024, 64, 0, stream>>>(qg, kg, vtg, out);
}

// Round 3
// 119.844 us; speedup vs baseline: 1.3777x; 1.0769x over previous
//
#include <hip/hip_runtime.h>
#include <hip/hip_bf16.h>

// Head: x[8,2048,768] fp32; Wk,Wq,Wv [768,64] fp32 -> out[8,2048,64] fp32
// q=xWq k=xWk v=xWv; att=softmax(q k^T/8); out=att v   (no causal mask)
//
// R3: raise occupancy.
//  - proj: 3072 blocks x 1 wave; each wave = 16 rows x ONE of {q,k,v}.
//  - attn: 1024 blocks x 4 waves; waves split SEQ (512 keys each) with
//    independent online softmax; LDS combine of (m,l,O) at the end.
//    XCD-aware block swizzle: one batch per XCD -> K/V L2-resident.

#define BATCH 8
#define SEQ   2048
#define CEMB  768
#define HEADD 64
// 0.125 (1/sqrt(64)) * log2(e): pre-scale logits so exp2 is direct
#define SCL 0.18033688011112042f

typedef __attribute__((ext_vector_type(4))) float f32x4;
typedef __attribute__((ext_vector_type(8))) short short8;
typedef __attribute__((ext_vector_type(4))) float fvec4;

__device__ __forceinline__ unsigned short f2bf(float f) {
    unsigned int u = __builtin_bit_cast(unsigned int, f);
    u += 0x7fffu + ((u >> 16) & 1u);   // round-to-nearest-even
    return (unsigned short)(u >> 16);
}

// ---------------- kernel 1: W -> W^T bf16  (wt[3][64][768]) ----------------
__global__ void wt_kernel(const float* __restrict__ Wq, const float* __restrict__ Wk,
                          const float* __restrict__ Wv, unsigned short* __restrict__ wt) {
    int idx = blockIdx.x * 256 + threadIdx.x;   // 3*64*768 = 147456
    int o = idx / 49152;
    int r = idx % 49152;
    int n = r / 768;
    int k = r % 768;
    const float* W = (o == 0) ? Wq : (o == 1) ? Wk : Wv;
    wt[idx] = f2bf(W[k * 64 + n]);
}

// ------ kernel 2: projections, 1 wave = 16 rows x one output matrix -------
__global__ __launch_bounds__(64) void proj_kernel(
        const float* __restrict__ x, const unsigned short* __restrict__ wt,
        unsigned short* __restrict__ qg, unsigned short* __restrict__ kg,
        unsigned short* __restrict__ vtg) {
    __shared__ __align__(16) unsigned short lds[64][20];   // qk path uses [16][20+]

    const int lane = threadIdx.x & 63;
    const int l15 = lane & 15;
    const int lq = lane >> 4;
    const int bid = blockIdx.x;
    const int tile = bid / 3;
    const int o = bid - tile * 3;          // 0=q 1=k 2=v
    const int row0 = tile * 16;

    f32x4 acc[4];
    #pragma unroll
    for (int f = 0; f < 4; ++f) acc[f] = f32x4{0.f, 0.f, 0.f, 0.f};

    const unsigned short* wbase = wt + o * 49152;

    for (int step = 0; step < 12; ++step) {
        const int k0 = step * 64;
        const float* xr = &x[(size_t)(row0 + l15) * CEMB + k0 + lq * 8];
        fvec4 x0 = *reinterpret_cast<const fvec4*>(xr);
        fvec4 x1 = *reinterpret_cast<const fvec4*>(xr + 4);
        fvec4 x2 = *reinterpret_cast<const fvec4*>(xr + 32);
        fvec4 x3 = *reinterpret_cast<const fvec4*>(xr + 36);
        short8 a0, a1;
        #pragma unroll
        for (int j = 0; j < 4; ++j) {
            a0[j]     = (short)f2bf(x0[j]);
            a0[4 + j] = (short)f2bf(x1[j]);
            a1[j]     = (short)f2bf(x2[j]);
            a1[4 + j] = (short)f2bf(x3[j]);
        }
        #pragma unroll
        for (int f = 0; f < 4; ++f) {
            const unsigned short* wp = &wbase[(f * 16 + l15) * CEMB + k0 + lq * 8];
            short8 b0 = *reinterpret_cast<const short8*>(wp);
            short8 b1 = *reinterpret_cast<const short8*>(wp + 32);
            acc[f] = __builtin_amdgcn_mfma_f32_16x16x32_bf16(a0, b0, acc[f], 0, 0, 0);
            acc[f] = __builtin_amdgcn_mfma_f32_16x16x32_bf16(a1, b1, acc[f], 0, 0, 0);
        }
    }

    if (o < 2) {
        // q,k row-major: repack through LDS -> coalesced 16B stores
        unsigned short* dst = o ? kg : qg;
        unsigned short (*lq16)[80] = reinterpret_cast<unsigned short (*)[80]>(&lds[0][0]);
        #pragma unroll
        for (int f = 0; f < 4; ++f)
            #pragma unroll
            for (int r = 0; r < 4; ++r)
                lq16[lq * 4 + r][f * 16 + l15] = f2bf(acc[f][r]);
        __syncthreads();
        #pragma unroll
        for (int i = 0; i < 2; ++i) {
            int chunk = lane + 64 * i;
            int m = chunk >> 3;
            int c0 = (chunk & 7) * 8;
            *reinterpret_cast<short8*>(&dst[(size_t)(row0 + m) * 64 + c0]) =
                *reinterpret_cast<const short8*>(&lq16[m][c0]);
        }
    } else {
        // v transposed: vtg[b][h][t]
        #pragma unroll
        for (int f = 0; f < 4; ++f)
            #pragma unroll
            for (int r = 0; r < 4; ++r)
                lds[f * 16 + l15][lq * 4 + r] = f2bf(acc[f][r]);   // lds[h][m]
        __syncthreads();
        const int bb = row0 >> 11;
        const int t0 = row0 & 2047;
        unsigned short* vp = &vtg[(size_t)bb * 64 * SEQ + (size_t)lane * SEQ + t0];
        *reinterpret_cast<short8*>(vp)     = *reinterpret_cast<const short8*>(&lds[lane][0]);
        *reinterpret_cast<short8*>(vp + 8) = *reinterpret_cast<const short8*>(&lds[lane][8]);
    }
}

// ---- kernel 3: flash attention, 4 waves/block split SEQ, LDS combine -----
__global__ __launch_bounds__(256, 4) void attn_kernel(
        const unsigned short* __restrict__ qg, const unsigned short* __restrict__ kg,
        const unsigned short* __restrict__ vtg, float* __restrict__ out) {
    __shared__ __align__(16) unsigned short pl[4][16][72];
    __shared__ __align__(16) float oL[4][16][64];
    __shared__ float mL[4][16];
    __shared__ float lL[4][16];

    const int tid = threadIdx.x;
    const int lane = tid & 63;
    const int wv = tid >> 6;           // wave 0..3: key chunk [512*wv, 512*wv+512)
    const int l15 = lane & 15;
    const int lq = lane >> 4;

    // XCD swizzle: 1024 blocks, 8 XCDs -> each XCD gets one batch (128 blocks)
    const int swz = (blockIdx.x & 7) * 128 + (blockIdx.x >> 3);
    const int b = swz >> 7;            // batch 0..7
    const int qt = swz & 127;          // 16-row query tile
    const size_t qrow0 = (size_t)b * SEQ + (size_t)qt * 16;

    const unsigned short* kbase = &kg[((size_t)b * SEQ + (size_t)wv * 512) * 64];
    const unsigned short* vbase = &vtg[(size_t)b * 64 * SEQ + (size_t)wv * 512];

    const short8 a0 = *reinterpret_cast<const short8*>(&qg[(qrow0 + l15) * 64 + lq * 8]);
    const short8 a1 = *reinterpret_cast<const short8*>(&qg[(qrow0 + l15) * 64 + 32 + lq * 8]);

    f32x4 o_acc[4];
    #pragma unroll
    for (int f = 0; f < 4; ++f) o_acc[f] = f32x4{0.f, 0.f, 0.f, 0.f};
    float m_run[4], l_run[4];
    #pragma unroll
    for (int r = 0; r < 4; ++r) { m_run[r] = -1e30f; l_run[r] = 0.f; }

    for (int kt = 0; kt < 8; ++kt) {
        const unsigned short* kp = kbase + (size_t)kt * 64 * 64;
        const unsigned short* vp = vbase + (size_t)kt * 64;
        short8 kf[8], vf[8];
        #pragma unroll
        for (int f = 0; f < 4; ++f) {
            kf[2 * f]     = *reinterpret_cast<const short8*>(&kp[(f * 16 + l15) * 64 + lq * 8]);
            kf[2 * f + 1] = *reinterpret_cast<const short8*>(&kp[(f * 16 + l15) * 64 + 32 + lq * 8]);
        }
        #pragma unroll
        for (int f = 0; f < 4; ++f) {
            vf[2 * f]     = *reinterpret_cast<const short8*>(&vp[(size_t)(f * 16 + l15) * SEQ + lq * 8]);
            vf[2 * f + 1] = *reinterpret_cast<const short8*>(&vp[(size_t)(f * 16 + l15) * SEQ + 32 + lq * 8]);
        }

        f32x4 s[4];
        #pragma unroll
        for (int f = 0; f < 4; ++f) {
            s[f] = f32x4{0.f, 0.f, 0.f, 0.f};
            s[f] = __builtin_amdgcn_mfma_f32_16x16x32_bf16(a0, kf[2 * f], s[f], 0, 0, 0);
            s[f] = __builtin_amdgcn_mfma_f32_16x16x32_bf16(a1, kf[2 * f + 1], s[f], 0, 0, 0);
        }
        #pragma unroll
        for (int f = 0; f < 4; ++f) s[f] *= SCL;

        float mnew[4], alpha[4], rsum[4];
        #pragma unroll
        for (int r = 0; r < 4; ++r) {
            float mx = fmaxf(fmaxf(s[0][r], s[1][r]), fmaxf(s[2][r], s[3][r]));
            mx = fmaxf(mx, __shfl_xor(mx, 1));
            mx = fmaxf(mx, __shfl_xor(mx, 2));
            mx = fmaxf(mx, __shfl_xor(mx, 4));
            mx = fmaxf(mx, __shfl_xor(mx, 8));
            mnew[r] = fmaxf(m_run[r], mx);
            alpha[r] = exp2f(m_run[r] - mnew[r]);
            m_run[r] = mnew[r];
            rsum[r] = 0.f;
        }
        #pragma unroll
        for (int f = 0; f < 4; ++f)
            #pragma unroll
            for (int r = 0; r < 4; ++r) {
                float pv = exp2f(s[f][r] - mnew[r]);
                rsum[r] += pv;
                pl[wv][lq * 4 + r][f * 16 + l15] = f2bf(pv);
            }
        #pragma unroll
        for (int r = 0; r < 4; ++r) {
            rsum[r] += __shfl_xor(rsum[r], 1);
            rsum[r] += __shfl_xor(rsum[r], 2);
            rsum[r] += __shfl_xor(rsum[r], 4);
            rsum[r] += __shfl_xor(rsum[r], 8);
            l_run[r] = l_run[r] * alpha[r] + rsum[r];
        }
        #pragma unroll
        for (int f = 0; f < 4; ++f)
            #pragma unroll
            for (int r = 0; r < 4; ++r) o_acc[f][r] *= alpha[r];

        short8 pa0 = *reinterpret_cast<const short8*>(&pl[wv][l15][lq * 8]);
        short8 pa1 = *reinterpret_cast<const short8*>(&pl[wv][l15][32 + lq * 8]);
        #pragma unroll
        for (int f = 0; f < 4; ++f) {
            o_acc[f] = __builtin_amdgcn_mfma_f32_16x16x32_bf16(pa0, vf[2 * f], o_acc[f], 0, 0, 0);
            o_acc[f] = __builtin_amdgcn_mfma_f32_16x16x32_bf16(pa1, vf[2 * f + 1], o_acc[f], 0, 0, 0);
        }
    }

    // ---- combine 4 waves' partial (m, l, O) through LDS ----
    #pragma unroll
    for (int r = 0; r < 4; ++r) {
        mL[wv][lq * 4 + r] = m_run[r];
        lL[wv][lq * 4 + r] = l_run[r];
    }
    #pragma unroll
    for (int f = 0; f < 4; ++f)
        #pragma unroll
        for (int r = 0; r < 4; ++r)
            oL[wv][lq * 4 + r][f * 16 + l15] = o_acc[f][r];
    __syncthreads();

    const int row = tid >> 4;          // 0..15
    const int c0 = (tid & 15) * 4;     // 0,4,...,60
    float M = fmaxf(fmaxf(mL[0][row], mL[1][row]), fmaxf(mL[2][row], mL[3][row]));
    float L = 0.f;
    fvec4 o = {0.f, 0.f, 0.f, 0.f};
    #pragma unroll
    for (int w = 0; w < 4; ++w) {
        float sc = exp2f(mL[w][row] - M);
        L += lL[w][row] * sc;
        fvec4 ov = *reinterpret_cast<const fvec4*>(&oL[w][row][c0]);
        o += ov * sc;
    }
    float inv = 1.0f / L;
    o *= inv;
    *reinterpret_cast<fvec4*>(&out[(qrow0 + row) * 64 + c0]) = o;
}

extern "C" void kernel_launch(void* const* d_in, const int* in_sizes, int n_in,
                              void* d_out, int out_size, void* d_ws, size_t ws_size,
                              hipStream_t stream) {
    (void)in_sizes; (void)n_in; (void)out_size; (void)ws_size;
    const float* x  = (const float*)d_in[0];
    const float* Wk = (const float*)d_in[1];   // setup_inputs order: x, Wk, Wq, Wv
    const float* Wq = (const float*)d_in[2];
    const float* Wv = (const float*)d_in[3];
    float* out = (float*)d_out;

    unsigned short* ws = (unsigned short*)d_ws;
    unsigned short* qg  = ws;                      // 16384*64
    unsigned short* kg  = ws + 1048576;            // 16384*64
    unsigned short* vtg = ws + 2097152;            // 8*64*2048
    unsigned short* wt  = ws + 3145728;            // 3*64*768

    wt_kernel<<<576, 256, 0, stream>>>(Wq, Wk, Wv, wt);
    proj_kernel<<<3072, 64, 0, stream>>>(x, wt, qg, kg, vtg);
    attn_kernel<<<1024, 256, 0, stream>>>(qg, kg, vtg, out);
}